// Round 1
// baseline (1337.172 us; speedup 1.0000x reference)
//
#include <hip/hip_runtime.h>
#include <math.h>

#define N_NODES 50000
#define N_EDGES 800000
#define HIDDEN  128
#define EDIM    32
#define NEG     0.2f

// ---------------------------------------------------------------------------
// sum of edge_attr columns (for mean): block-partial sums + one atomic/thread
__global__ void reduce_ea_kernel(const float* __restrict__ ea,
                                 float* __restrict__ sum_ea) {
    int t = threadIdx.x;
    int col = t & 31;
    int r = blockIdx.x * 8 + (t >> 5);
    int stride = gridDim.x * 8;
    float local = 0.f;
    for (; r < N_EDGES; r += stride) local += ea[(size_t)r * EDIM + col];
    atomicAdd(&sum_ea[col], local);
}

// ---------------------------------------------------------------------------
// ce1 = We1 @ ae1, ce2 = We2 @ ae2 (each [32]); self-loop edge constants
// consts[0:32]=ce1, consts[32:64]=ce2, consts[64]=selfc1, consts[65]=selfc2
__global__ void prep_kernel(const float* __restrict__ We1, const float* __restrict__ ae1,
                            const float* __restrict__ We2, const float* __restrict__ ae2,
                            const float* __restrict__ sum_ea, float* __restrict__ consts) {
    int t = threadIdx.x;
    if (t < 32) {
        float acc = 0.f;
        for (int k = 0; k < HIDDEN; k++) acc += We1[t * HIDDEN + k] * ae1[k];
        consts[t] = acc;
    } else if (t < 64) {
        int j = t - 32;
        float acc = 0.f;
        for (int k = 0; k < HIDDEN; k++) acc += We2[j * HIDDEN + k] * ae2[k];
        consts[32 + j] = acc;
    }
    __syncthreads();
    if (t == 0) {
        float s1 = 0.f, s2 = 0.f;
        for (int c = 0; c < 32; c++) {
            float m = sum_ea[c] / (float)N_EDGES;
            s1 += m * consts[c];
            s2 += m * consts[32 + c];
        }
        consts[64] = s1;
        consts[65] = s2;
    }
}

// ---------------------------------------------------------------------------
// h = x @ W   (one block per row, 128 threads = 128 output channels)
// fused: alpha[row] = h_row . a_s ; beta[row] = h_row . a_d
__global__ void gemm_node_kernel(const float* __restrict__ x, const float* __restrict__ W,
                                 const float* __restrict__ a_s, const float* __restrict__ a_d,
                                 float* __restrict__ h, float* __restrict__ alpha,
                                 float* __restrict__ beta) {
    __shared__ float xr[HIDDEN];
    __shared__ float pa[2], pb[2];
    int row = blockIdx.x, t = threadIdx.x;
    xr[t] = x[(size_t)row * HIDDEN + t];
    __syncthreads();
    float acc = 0.f;
#pragma unroll 16
    for (int k = 0; k < HIDDEN; k++) acc += xr[k] * W[k * HIDDEN + t];
    h[(size_t)row * HIDDEN + t] = acc;
    float va = acc * a_s[t];
    float vb = acc * a_d[t];
    for (int off = 32; off > 0; off >>= 1) {
        va += __shfl_down(va, off, 64);
        vb += __shfl_down(vb, off, 64);
    }
    if ((t & 63) == 0) { pa[t >> 6] = va; pb[t >> 6] = vb; }
    __syncthreads();
    if (t == 0) { alpha[row] = pa[0] + pa[1]; beta[row] = pb[0] + pb[1]; }
}

// ---------------------------------------------------------------------------
// per real edge: logit -> leaky_relu -> exp ; store ex[e]; atomic denom s[dst]
__global__ void edge_pass_kernel(const int* __restrict__ src, const int* __restrict__ dst,
                                 const float* __restrict__ ea,
                                 const float* __restrict__ alpha, const float* __restrict__ beta,
                                 const float* __restrict__ ce,
                                 float* __restrict__ s, float* __restrict__ ex) {
    __shared__ float cs[32];
    int t = threadIdx.x;
    if (t < 32) cs[t] = ce[t];
    __syncthreads();
    int e = blockIdx.x * blockDim.x + t;
    if (e >= N_EDGES) return;
    const float4* ep = (const float4*)(ea + (size_t)e * EDIM);
    float dotv = 0.f;
#pragma unroll
    for (int i = 0; i < 8; i++) {
        float4 v = ep[i];
        dotv += v.x * cs[4 * i] + v.y * cs[4 * i + 1] + v.z * cs[4 * i + 2] + v.w * cs[4 * i + 3];
    }
    float l = alpha[src[e]] + beta[dst[e]] + dotv;
    l = l > 0.f ? l : NEG * l;
    float e_ = expf(l);
    ex[e] = e_;
    atomicAdd(&s[dst[e]], e_);
}

// ---------------------------------------------------------------------------
// scatter-add numerators: num[dst, c] += ex[e] * h[src, c]
__global__ void aggregate_kernel(const int* __restrict__ src, const int* __restrict__ dst,
                                 const float* __restrict__ ex, const float* __restrict__ h,
                                 float* __restrict__ num) {
    size_t idx = (size_t)blockIdx.x * blockDim.x + threadIdx.x;
    int e = (int)(idx >> 7);
    int c = (int)(idx & 127);
    if (e >= N_EDGES) return;
    float w = ex[e];
    float hv = h[(size_t)src[e] * HIDDEN + c];
    atomicAdd(&num[(size_t)dst[e] * HIDDEN + c], w * hv);
}

// ---------------------------------------------------------------------------
// conv1 finalize: add self-loop term, divide, +bias, ReLU  (writes over h buf)
__global__ void finalize1_kernel(const float* __restrict__ num, const float* __restrict__ h,
                                 const float* __restrict__ alpha, const float* __restrict__ beta,
                                 const float* __restrict__ s, const float* __restrict__ b,
                                 const float* __restrict__ selfc, float* __restrict__ outh) {
    int i = blockIdx.x, t = threadIdx.x;
    float l = alpha[i] + beta[i] + selfc[0];
    l = l > 0.f ? l : NEG * l;
    float exi = expf(l);
    float denom = s[i] + exi + 1e-16f;
    size_t o = (size_t)i * HIDDEN + t;
    float v = (num[o] + exi * h[o]) / denom + b[t];
    outh[o] = fmaxf(v, 0.f);
}

// ---------------------------------------------------------------------------
// conv2 finalize fused with final linear (HID->1) + ReLU
__global__ void finalize2_kernel(const float* __restrict__ num, const float* __restrict__ h,
                                 const float* __restrict__ alpha, const float* __restrict__ beta,
                                 const float* __restrict__ s, const float* __restrict__ b,
                                 const float* __restrict__ selfc,
                                 const float* __restrict__ Wl, const float* __restrict__ bl,
                                 float* __restrict__ out) {
    __shared__ float p[2];
    int i = blockIdx.x, t = threadIdx.x;
    float l = alpha[i] + beta[i] + selfc[0];
    l = l > 0.f ? l : NEG * l;
    float exi = expf(l);
    float denom = s[i] + exi + 1e-16f;
    size_t o = (size_t)i * HIDDEN + t;
    float v = (num[o] + exi * h[o]) / denom + b[t];
    float contrib = v * Wl[t];
    for (int off = 32; off > 0; off >>= 1) contrib += __shfl_down(contrib, off, 64);
    if ((t & 63) == 0) p[t >> 6] = contrib;
    __syncthreads();
    if (t == 0) out[i] = fmaxf(p[0] + p[1] + bl[0], 0.f);
}

// ---------------------------------------------------------------------------
extern "C" void kernel_launch(void* const* d_in, const int* in_sizes, int n_in,
                              void* d_out, int out_size, void* d_ws, size_t ws_size,
                              hipStream_t stream) {
    const float* x   = (const float*)d_in[0];
    const int*   src = (const int*)  d_in[1];
    const int*   dst = (const int*)  d_in[2];
    const float* ea  = (const float*)d_in[3];
    const float* W1  = (const float*)d_in[4];
    const float* We1 = (const float*)d_in[5];
    const float* as1 = (const float*)d_in[6];
    const float* ad1 = (const float*)d_in[7];
    const float* ae1 = (const float*)d_in[8];
    const float* b1  = (const float*)d_in[9];
    const float* W2  = (const float*)d_in[10];
    const float* We2 = (const float*)d_in[11];
    const float* as2 = (const float*)d_in[12];
    const float* ad2 = (const float*)d_in[13];
    const float* ae2 = (const float*)d_in[14];
    const float* b2  = (const float*)d_in[15];
    const float* Wl  = (const float*)d_in[16];
    const float* bl  = (const float*)d_in[17];
    float* out = (float*)d_out;

    float* ws     = (float*)d_ws;
    float* A      = ws;                       // [N*128]  h1 -> h2
    float* B      = A + (size_t)N_NODES * HIDDEN; // [N*128]  num1 -> hlin2 -> ...
    float* alpha  = B + (size_t)N_NODES * HIDDEN; // [N]
    float* beta   = alpha + N_NODES;          // [N]
    float* s      = beta + N_NODES;           // [N]
    float* ex     = s + N_NODES;              // [E]
    float* sum_ea = ex + N_EDGES;             // [32]
    float* consts = sum_ea + 32;              // [66]

    const int EB = (N_EDGES + 255) / 256;                  // edge_pass blocks
    const int AB = (int)(((size_t)N_EDGES * HIDDEN) / 256); // aggregate blocks

    // ---- shared prep ----
    hipMemsetAsync(sum_ea, 0, 32 * sizeof(float), stream);
    reduce_ea_kernel<<<1024, 256, 0, stream>>>(ea, sum_ea);
    prep_kernel<<<1, 64, 0, stream>>>(We1, ae1, We2, ae2, sum_ea, consts);

    // ---- conv1 ----
    hipMemsetAsync(s, 0, N_NODES * sizeof(float), stream);
    hipMemsetAsync(B, 0, (size_t)N_NODES * HIDDEN * sizeof(float), stream);
    gemm_node_kernel<<<N_NODES, 128, 0, stream>>>(x, W1, as1, ad1, A, alpha, beta);
    edge_pass_kernel<<<EB, 256, 0, stream>>>(src, dst, ea, alpha, beta, consts, s, ex);
    aggregate_kernel<<<AB, 256, 0, stream>>>(src, dst, ex, A, B);
    finalize1_kernel<<<N_NODES, 128, 0, stream>>>(B, A, alpha, beta, s, b1, consts + 64, A);

    // ---- conv2 ----
    gemm_node_kernel<<<N_NODES, 128, 0, stream>>>(A, W2, as2, ad2, B, alpha, beta);
    hipMemsetAsync(A, 0, (size_t)N_NODES * HIDDEN * sizeof(float), stream);
    hipMemsetAsync(s, 0, N_NODES * sizeof(float), stream);
    edge_pass_kernel<<<EB, 256, 0, stream>>>(src, dst, ea, alpha, beta, consts + 32, s, ex);
    aggregate_kernel<<<AB, 256, 0, stream>>>(src, dst, ex, B, A);
    finalize2_kernel<<<N_NODES, 128, 0, stream>>>(A, B, alpha, beta, s, b2, consts + 65,
                                                  Wl, bl, out);
}

// Round 2
// 868.061 us; speedup vs baseline: 1.5404x; 1.5404x over previous
//
#include <hip/hip_runtime.h>
#include <math.h>

#define N_NODES 50000
#define N_EDGES 800000
#define HIDDEN  128
#define EDIM    32
#define NEG     0.2f

// ---------------------------------------------------------------------------
// sum of edge_attr columns (for mean): block-partial sums + one atomic/thread
__global__ void reduce_ea_kernel(const float* __restrict__ ea,
                                 float* __restrict__ sum_ea) {
    int t = threadIdx.x;
    int col = t & 31;
    int r = blockIdx.x * 8 + (t >> 5);
    int stride = gridDim.x * 8;
    float local = 0.f;
    for (; r < N_EDGES; r += stride) local += ea[(size_t)r * EDIM + col];
    atomicAdd(&sum_ea[col], local);
}

// ---------------------------------------------------------------------------
// ce1 = We1 @ ae1, ce2 = We2 @ ae2 (each [32]); self-loop edge constants
// consts[0:32]=ce1, consts[32:64]=ce2, consts[64]=selfc1, consts[65]=selfc2
__global__ void prep_kernel(const float* __restrict__ We1, const float* __restrict__ ae1,
                            const float* __restrict__ We2, const float* __restrict__ ae2,
                            const float* __restrict__ sum_ea, float* __restrict__ consts) {
    int t = threadIdx.x;
    if (t < 32) {
        float acc = 0.f;
        for (int k = 0; k < HIDDEN; k++) acc += We1[t * HIDDEN + k] * ae1[k];
        consts[t] = acc;
    } else if (t < 64) {
        int j = t - 32;
        float acc = 0.f;
        for (int k = 0; k < HIDDEN; k++) acc += We2[j * HIDDEN + k] * ae2[k];
        consts[32 + j] = acc;
    }
    __syncthreads();
    if (t == 0) {
        float s1 = 0.f, s2 = 0.f;
        for (int c = 0; c < 32; c++) {
            float m = sum_ea[c] / (float)N_EDGES;
            s1 += m * consts[c];
            s2 += m * consts[32 + c];
        }
        consts[64] = s1;
        consts[65] = s2;
    }
}

// ---------------------------------------------------------------------------
// CSR build step 1: in-degree histogram
__global__ void hist_kernel(const int* __restrict__ dst, int* __restrict__ count) {
    int e = blockIdx.x * blockDim.x + threadIdx.x;
    if (e < N_EDGES) atomicAdd(&count[dst[e]], 1);
}

// CSR build step 2: exclusive scan of count -> off_work (single block)
#define SCAN_T 1024
__global__ void scan_kernel(const int* __restrict__ count, int* __restrict__ off_work) {
    __shared__ int part[SCAN_T];
    int t = threadIdx.x;
    const int CH = (N_NODES + SCAN_T - 1) / SCAN_T;   // 49
    int base = t * CH;
    int s = 0;
    for (int i = 0; i < CH; i++) {
        int idx = base + i;
        if (idx < N_NODES) s += count[idx];
    }
    part[t] = s;
    __syncthreads();
    // Hillis-Steele inclusive scan over 1024 partials
    for (int off = 1; off < SCAN_T; off <<= 1) {
        int v = (t >= off) ? part[t - off] : 0;
        __syncthreads();
        part[t] += v;
        __syncthreads();
    }
    int run = (t == 0) ? 0 : part[t - 1];   // exclusive prefix of this chunk
    for (int i = 0; i < CH; i++) {
        int idx = base + i;
        if (idx < N_NODES) { off_work[idx] = run; run += count[idx]; }
    }
}

// CSR build step 3: scatter edges into dst-sorted order.
// After this kernel, off_work[i] == end offset of segment i (== off[i+1]),
// and off_work[i-1] == start offset of segment i.
__global__ void scatter_kernel(const int* __restrict__ src, const int* __restrict__ dst,
                               int* __restrict__ off_work,
                               int* __restrict__ src_p, int* __restrict__ ipos) {
    int e = blockIdx.x * blockDim.x + threadIdx.x;
    if (e >= N_EDGES) return;
    int pos = atomicAdd(&off_work[dst[e]], 1);
    src_p[pos] = src[e];
    ipos[e] = pos;
}

// ---------------------------------------------------------------------------
// h = x @ W   (one block per row, 128 threads = 128 output channels)
// fused: alpha[row] = h_row . a_s ; beta[row] = h_row . a_d
__global__ void gemm_node_kernel(const float* __restrict__ x, const float* __restrict__ W,
                                 const float* __restrict__ a_s, const float* __restrict__ a_d,
                                 float* __restrict__ h, float* __restrict__ alpha,
                                 float* __restrict__ beta) {
    __shared__ float xr[HIDDEN];
    __shared__ float pa[2], pb[2];
    int row = blockIdx.x, t = threadIdx.x;
    xr[t] = x[(size_t)row * HIDDEN + t];
    __syncthreads();
    float acc = 0.f;
#pragma unroll 16
    for (int k = 0; k < HIDDEN; k++) acc += xr[k] * W[k * HIDDEN + t];
    h[(size_t)row * HIDDEN + t] = acc;
    float va = acc * a_s[t];
    float vb = acc * a_d[t];
    for (int off = 32; off > 0; off >>= 1) {
        va += __shfl_down(va, off, 64);
        vb += __shfl_down(vb, off, 64);
    }
    if ((t & 63) == 0) { pa[t >> 6] = va; pb[t >> 6] = vb; }
    __syncthreads();
    if (t == 0) { alpha[row] = pa[0] + pa[1]; beta[row] = pb[0] + pb[1]; }
}

// ---------------------------------------------------------------------------
// per real edge: logit -> leaky_relu -> exp ; store into dst-sorted slot
__global__ void edge_pass_kernel(const int* __restrict__ src, const int* __restrict__ dst,
                                 const float* __restrict__ ea,
                                 const float* __restrict__ alpha, const float* __restrict__ beta,
                                 const float* __restrict__ ce,
                                 const int* __restrict__ ipos, float* __restrict__ ex_p) {
    __shared__ float cs[32];
    int t = threadIdx.x;
    if (t < 32) cs[t] = ce[t];
    __syncthreads();
    int e = blockIdx.x * blockDim.x + t;
    if (e >= N_EDGES) return;
    const float4* ep = (const float4*)(ea + (size_t)e * EDIM);
    float dotv = 0.f;
#pragma unroll
    for (int i = 0; i < 8; i++) {
        float4 v = ep[i];
        dotv += v.x * cs[4 * i] + v.y * cs[4 * i + 1] + v.z * cs[4 * i + 2] + v.w * cs[4 * i + 3];
    }
    float l = alpha[src[e]] + beta[dst[e]] + dotv;
    l = l > 0.f ? l : NEG * l;
    ex_p[ipos[e]] = expf(l);
}

// ---------------------------------------------------------------------------
// Gather-aggregate, fused with softmax denominator + self-loop + finalize.
// One block per destination node; 128 threads = channels.
// FINAL==0: write relu(v + b) to outp[N,128]   (conv1)
// FINAL==1: out[i] = relu(dot(v + b, Wl) + bl) (conv2 + final linear)
template<int FINAL>
__global__ void agg_kernel(const int* __restrict__ off_work,
                           const int* __restrict__ src_p,
                           const float* __restrict__ ex_p,
                           const float* __restrict__ h,
                           const float* __restrict__ alpha, const float* __restrict__ beta,
                           const float* __restrict__ b, const float* __restrict__ selfc,
                           const float* __restrict__ Wl, const float* __restrict__ bl,
                           float* __restrict__ outp) {
    __shared__ int   s_src[128];
    __shared__ float s_w[128];
    __shared__ float p[2];
    int i = blockIdx.x, t = threadIdx.x;
    int start = (i == 0) ? 0 : off_work[i - 1];
    int end   = off_work[i];
    float acc = 0.f, wsum = 0.f;
    for (int cb = start; cb < end; cb += 128) {
        int n = min(128, end - cb);
        __syncthreads();
        if (t < n) { s_src[t] = src_p[cb + t]; s_w[t] = ex_p[cb + t]; }
        __syncthreads();
        for (int j = 0; j < n; j++) {
            float w = s_w[j];
            acc  += w * h[(size_t)s_src[j] * HIDDEN + t];
            wsum += w;
        }
    }
    // self-loop edge
    float l = alpha[i] + beta[i] + selfc[0];
    l = l > 0.f ? l : NEG * l;
    float exi = expf(l);
    float denom = wsum + exi + 1e-16f;
    float v = (acc + exi * h[(size_t)i * HIDDEN + t]) / denom + b[t];
    if (FINAL == 0) {
        outp[(size_t)i * HIDDEN + t] = fmaxf(v, 0.f);
    } else {
        float contrib = v * Wl[t];
        for (int off = 32; off > 0; off >>= 1) contrib += __shfl_down(contrib, off, 64);
        if ((t & 63) == 0) p[t >> 6] = contrib;
        __syncthreads();
        if (t == 0) outp[i] = fmaxf(p[0] + p[1] + bl[0], 0.f);
    }
}

// ---------------------------------------------------------------------------
extern "C" void kernel_launch(void* const* d_in, const int* in_sizes, int n_in,
                              void* d_out, int out_size, void* d_ws, size_t ws_size,
                              hipStream_t stream) {
    const float* x   = (const float*)d_in[0];
    const int*   src = (const int*)  d_in[1];
    const int*   dst = (const int*)  d_in[2];
    const float* ea  = (const float*)d_in[3];
    const float* W1  = (const float*)d_in[4];
    const float* We1 = (const float*)d_in[5];
    const float* as1 = (const float*)d_in[6];
    const float* ad1 = (const float*)d_in[7];
    const float* ae1 = (const float*)d_in[8];
    const float* b1  = (const float*)d_in[9];
    const float* W2  = (const float*)d_in[10];
    const float* We2 = (const float*)d_in[11];
    const float* as2 = (const float*)d_in[12];
    const float* ad2 = (const float*)d_in[13];
    const float* ae2 = (const float*)d_in[14];
    const float* b2  = (const float*)d_in[15];
    const float* Wl  = (const float*)d_in[16];
    const float* bl  = (const float*)d_in[17];
    float* out = (float*)d_out;

    float* ws     = (float*)d_ws;
    float* A      = ws;                           // [N*128]  h1, then h2
    float* B      = A + (size_t)N_NODES * HIDDEN; // [N*128]  out1 (conv1 result)
    float* alpha  = B + (size_t)N_NODES * HIDDEN; // [N]
    float* beta   = alpha + N_NODES;              // [N]
    float* ex_p   = beta + N_NODES;               // [E] dst-sorted edge weights
    float* sum_ea = ex_p + N_EDGES;               // [32]
    float* consts = sum_ea + 32;                  // [66]
    int* count    = (int*)(consts + 66);          // [N]
    int* off_work = count + N_NODES;              // [N]
    int* src_p    = off_work + N_NODES;           // [E] dst-sorted src ids
    int* ipos     = src_p + N_EDGES;              // [E] edge -> sorted slot

    const int EB = (N_EDGES + 255) / 256;

    // ---- shared prep: ea mean, edge-logit constants, CSR build ----
    hipMemsetAsync(sum_ea, 0, 32 * sizeof(float), stream);
    hipMemsetAsync(count, 0, N_NODES * sizeof(int), stream);
    reduce_ea_kernel<<<1024, 256, 0, stream>>>(ea, sum_ea);
    prep_kernel<<<1, 64, 0, stream>>>(We1, ae1, We2, ae2, sum_ea, consts);
    hist_kernel<<<EB, 256, 0, stream>>>(dst, count);
    scan_kernel<<<1, SCAN_T, 0, stream>>>(count, off_work);
    scatter_kernel<<<EB, 256, 0, stream>>>(src, dst, off_work, src_p, ipos);

    // ---- conv1 ----
    gemm_node_kernel<<<N_NODES, 128, 0, stream>>>(x, W1, as1, ad1, A, alpha, beta);
    edge_pass_kernel<<<EB, 256, 0, stream>>>(src, dst, ea, alpha, beta, consts, ipos, ex_p);
    agg_kernel<0><<<N_NODES, 128, 0, stream>>>(off_work, src_p, ex_p, A, alpha, beta,
                                               b1, consts + 64, nullptr, nullptr, B);

    // ---- conv2 (+ final linear fused) ----
    gemm_node_kernel<<<N_NODES, 128, 0, stream>>>(B, W2, as2, ad2, A, alpha, beta);
    edge_pass_kernel<<<EB, 256, 0, stream>>>(src, dst, ea, alpha, beta, consts + 32, ipos, ex_p);
    agg_kernel<1><<<N_NODES, 128, 0, stream>>>(off_work, src_p, ex_p, A, alpha, beta,
                                               b2, consts + 65, Wl, bl, out);
}

// Round 3
// 845.614 us; speedup vs baseline: 1.5813x; 1.0265x over previous
//
#include <hip/hip_runtime.h>
#include <math.h>

#define N_NODES 50000
#define N_EDGES 800000
#define HIDDEN  128
#define EDIM    32
#define NEG     0.2f

// ---------------------------------------------------------------------------
// ce1 = We1 @ ae1, ce2 = We2 @ ae2 (each [32])
// consts[0:32]=ce1, consts[32:64]=ce2
__global__ void prep_kernel(const float* __restrict__ We1, const float* __restrict__ ae1,
                            const float* __restrict__ We2, const float* __restrict__ ae2,
                            float* __restrict__ consts) {
    int t = threadIdx.x;
    if (t < 32) {
        float acc = 0.f;
        for (int k = 0; k < HIDDEN; k++) acc += We1[t * HIDDEN + k] * ae1[k];
        consts[t] = acc;
    } else if (t < 64) {
        int j = t - 32;
        float acc = 0.f;
        for (int k = 0; k < HIDDEN; k++) acc += We2[j * HIDDEN + k] * ae2[k];
        consts[32 + j] = acc;
    }
}

// ---------------------------------------------------------------------------
// CSR build step 1: in-degree histogram
__global__ void hist_kernel(const int* __restrict__ dst, int* __restrict__ count) {
    int e = blockIdx.x * blockDim.x + threadIdx.x;
    if (e < N_EDGES) atomicAdd(&count[dst[e]], 1);
}

// CSR build step 2: exclusive scan of count -> off_work (single block)
#define SCAN_T 1024
__global__ void scan_kernel(const int* __restrict__ count, int* __restrict__ off_work) {
    __shared__ int part[SCAN_T];
    int t = threadIdx.x;
    const int CH = (N_NODES + SCAN_T - 1) / SCAN_T;   // 49
    int base = t * CH;
    int s = 0;
    for (int i = 0; i < CH; i++) {
        int idx = base + i;
        if (idx < N_NODES) s += count[idx];
    }
    part[t] = s;
    __syncthreads();
    for (int off = 1; off < SCAN_T; off <<= 1) {
        int v = (t >= off) ? part[t - off] : 0;
        __syncthreads();
        part[t] += v;
        __syncthreads();
    }
    int run = (t == 0) ? 0 : part[t - 1];
    for (int i = 0; i < CH; i++) {
        int idx = base + i;
        if (idx < N_NODES) { off_work[idx] = run; run += count[idx]; }
    }
}

// CSR build step 3: scatter edges into dst-sorted order.
// After: off_work[i] == end offset of segment i; off_work[i-1] == start.
__global__ void scatter_kernel(const int* __restrict__ src, const int* __restrict__ dst,
                               int* __restrict__ off_work,
                               int* __restrict__ src_p, int* __restrict__ ipos) {
    int e = blockIdx.x * blockDim.x + threadIdx.x;
    if (e >= N_EDGES) return;
    int pos = atomicAdd(&off_work[dst[e]], 1);
    src_p[pos] = src[e];
    ipos[e] = pos;
}

// ---------------------------------------------------------------------------
// h = x @ W with W staged in LDS; 100 rows/block, 4-row chunks, 2 rows/thread.
// fused: alpha[row] = h_row . a_s ; beta[row] = h_row . a_d
#define GEMM_ROWS 100
#define GEMM_BLOCKS (N_NODES / GEMM_ROWS)   // 500
__global__ void __launch_bounds__(256)
gemm_node_kernel(const float* __restrict__ x, const float* __restrict__ W,
                 const float* __restrict__ a_s, const float* __restrict__ a_d,
                 float* __restrict__ h, float* __restrict__ alpha,
                 float* __restrict__ beta) {
    __shared__ float Wl[HIDDEN][HIDDEN];      // 64 KB, [k][col]
    __shared__ float xs[4][HIDDEN];
    __shared__ float pa[4][2], pb[4][2];
    int t = threadIdx.x;
    // stage W (coalesced float4)
    {
        float4* Wl4 = (float4*)&Wl[0][0];
        const float4* W4 = (const float4*)W;
#pragma unroll
        for (int i = 0; i < 16; i++) Wl4[i * 256 + t] = W4[i * 256 + t];
    }
    int col = t & 127;
    int rq  = t >> 7;          // 0/1 -> which row pair
    int wv  = t >> 6;          // wave id 0..3
    float as_c = a_s[col], ad_c = a_d[col];
    int row_base = blockIdx.x * GEMM_ROWS;
    for (int r0 = row_base; r0 < row_base + GEMM_ROWS; r0 += 4) {
        __syncthreads();       // protect xs/pa from previous iteration
        {
            int j = t >> 7, c = t & 127;
            xs[j][c]     = x[(size_t)(r0 + j) * HIDDEN + c];
            xs[j + 2][c] = x[(size_t)(r0 + j + 2) * HIDDEN + c];
        }
        __syncthreads();
        int ra = r0 + 2 * rq;
        float acc_a = 0.f, acc_b = 0.f;
#pragma unroll 32
        for (int k = 0; k < HIDDEN; k++) {
            float w = Wl[k][col];
            acc_a += xs[2 * rq][k] * w;
            acc_b += xs[2 * rq + 1][k] * w;
        }
        h[(size_t)ra * HIDDEN + col]       = acc_a;
        h[(size_t)(ra + 1) * HIDDEN + col] = acc_b;
        float vaa = acc_a * as_c, vab = acc_b * as_c;
        float vba = acc_a * ad_c, vbb = acc_b * ad_c;
        for (int off = 32; off > 0; off >>= 1) {
            vaa += __shfl_down(vaa, off, 64);
            vab += __shfl_down(vab, off, 64);
            vba += __shfl_down(vba, off, 64);
            vbb += __shfl_down(vbb, off, 64);
        }
        if ((t & 63) == 0) {
            pa[wv][0] = vaa; pa[wv][1] = vab;
            pb[wv][0] = vba; pb[wv][1] = vbb;
        }
        __syncthreads();
        if (t < 4) {
            int rqj = t >> 1, sub = t & 1;
            alpha[r0 + t] = pa[2 * rqj][sub] + pa[2 * rqj + 1][sub];
            beta[r0 + t]  = pb[2 * rqj][sub] + pb[2 * rqj + 1][sub];
        }
    }
}

// ---------------------------------------------------------------------------
// per real edge: logit -> leaky_relu -> exp ; store into dst-sorted slot.
// Also accumulates sum of raw dotv (for the self-loop mean constant).
__global__ void edge_pass_kernel(const int* __restrict__ src, const int* __restrict__ dst,
                                 const float* __restrict__ ea,
                                 const float* __restrict__ alpha, const float* __restrict__ beta,
                                 const float* __restrict__ ce,
                                 const int* __restrict__ ipos, float* __restrict__ ex_p,
                                 float* __restrict__ sum_dotv) {
    __shared__ float cs[32];
    int t = threadIdx.x;
    if (t < 32) cs[t] = ce[t];
    __syncthreads();
    int e = blockIdx.x * blockDim.x + t;   // N_EDGES % 256 == 0: all lanes active
    const float4* ep = (const float4*)(ea + (size_t)e * EDIM);
    float dotv = 0.f;
#pragma unroll
    for (int i = 0; i < 8; i++) {
        float4 v = ep[i];
        dotv += v.x * cs[4 * i] + v.y * cs[4 * i + 1] + v.z * cs[4 * i + 2] + v.w * cs[4 * i + 3];
    }
    // wave-reduce raw dotv for the mean-edge-attr self-loop constant
    float dsum = dotv;
    for (int off = 32; off > 0; off >>= 1) dsum += __shfl_down(dsum, off, 64);
    if ((t & 63) == 0) atomicAdd(sum_dotv, dsum);
    float l = alpha[src[e]] + beta[dst[e]] + dotv;
    l = l > 0.f ? l : NEG * l;
    ex_p[ipos[e]] = expf(l);
}

// ---------------------------------------------------------------------------
// Gather-aggregate, fused with softmax denominator + self-loop + finalize.
// One block per destination node; 128 threads = channels.
// FINAL==0: write relu(v + b) to outp[N,128]   (conv1)
// FINAL==1: out[i] = relu(dot(v + b, Wl) + bl) (conv2 + final linear)
template<int FINAL>
__global__ void agg_kernel(const int* __restrict__ off_work,
                           const int* __restrict__ src_p,
                           const float* __restrict__ ex_p,
                           const float* __restrict__ h,
                           const float* __restrict__ alpha, const float* __restrict__ beta,
                           const float* __restrict__ b, const float* __restrict__ sum_dotv,
                           const float* __restrict__ Wl, const float* __restrict__ bl,
                           float* __restrict__ outp) {
    __shared__ int   s_src[128];
    __shared__ float s_w[128];
    __shared__ float p[2];
    int i = blockIdx.x, t = threadIdx.x;
    int start = (i == 0) ? 0 : off_work[i - 1];
    int end   = off_work[i];
    float acc = 0.f, wsum = 0.f;
    for (int cb = start; cb < end; cb += 128) {
        int n = min(128, end - cb);
        __syncthreads();
        if (t < n) { s_src[t] = src_p[cb + t]; s_w[t] = ex_p[cb + t]; }
        __syncthreads();
        for (int j = 0; j < n; j++) {
            float w = s_w[j];
            acc  += w * h[(size_t)s_src[j] * HIDDEN + t];
            wsum += w;
        }
    }
    // self-loop edge (edge feature = mean over edges of dotv)
    float selfc = sum_dotv[0] * (1.f / (float)N_EDGES);
    float l = alpha[i] + beta[i] + selfc;
    l = l > 0.f ? l : NEG * l;
    float exi = expf(l);
    float denom = wsum + exi + 1e-16f;
    float v = (acc + exi * h[(size_t)i * HIDDEN + t]) / denom + b[t];
    if (FINAL == 0) {
        outp[(size_t)i * HIDDEN + t] = fmaxf(v, 0.f);
    } else {
        float contrib = v * Wl[t];
        for (int off = 32; off > 0; off >>= 1) contrib += __shfl_down(contrib, off, 64);
        if ((t & 63) == 0) p[t >> 6] = contrib;
        __syncthreads();
        if (t == 0) outp[i] = fmaxf(p[0] + p[1] + bl[0], 0.f);
    }
}

// ---------------------------------------------------------------------------
extern "C" void kernel_launch(void* const* d_in, const int* in_sizes, int n_in,
                              void* d_out, int out_size, void* d_ws, size_t ws_size,
                              hipStream_t stream) {
    const float* x   = (const float*)d_in[0];
    const int*   src = (const int*)  d_in[1];
    const int*   dst = (const int*)  d_in[2];
    const float* ea  = (const float*)d_in[3];
    const float* W1  = (const float*)d_in[4];
    const float* We1 = (const float*)d_in[5];
    const float* as1 = (const float*)d_in[6];
    const float* ad1 = (const float*)d_in[7];
    const float* ae1 = (const float*)d_in[8];
    const float* b1  = (const float*)d_in[9];
    const float* W2  = (const float*)d_in[10];
    const float* We2 = (const float*)d_in[11];
    const float* as2 = (const float*)d_in[12];
    const float* ad2 = (const float*)d_in[13];
    const float* ae2 = (const float*)d_in[14];
    const float* b2  = (const float*)d_in[15];
    const float* Wl  = (const float*)d_in[16];
    const float* bl  = (const float*)d_in[17];
    float* out = (float*)d_out;

    float* ws     = (float*)d_ws;
    float* A      = ws;                           // [N*128]  h1, then h2
    float* B      = A + (size_t)N_NODES * HIDDEN; // [N*128]  out1 (conv1 result)
    float* alpha  = B + (size_t)N_NODES * HIDDEN; // [N]
    float* beta   = alpha + N_NODES;              // [N]
    float* ex_p   = beta + N_NODES;               // [E] dst-sorted edge weights
    float* consts = ex_p + N_EDGES;               // [64] ce1, ce2
    float* sdv    = consts + 64;                  // [2] sum of dotv per layer
    int* count    = (int*)(sdv + 2);              // [N]
    int* off_work = count + N_NODES;              // [N]
    int* src_p    = off_work + N_NODES;           // [E] dst-sorted src ids
    int* ipos     = src_p + N_EDGES;              // [E] edge -> sorted slot

    const int EB = (N_EDGES + 255) / 256;

    // ---- shared prep: edge-logit constants, CSR build ----
    hipMemsetAsync(count, 0, N_NODES * sizeof(int), stream);
    hipMemsetAsync(sdv, 0, 2 * sizeof(float), stream);
    prep_kernel<<<1, 64, 0, stream>>>(We1, ae1, We2, ae2, consts);
    hist_kernel<<<EB, 256, 0, stream>>>(dst, count);
    scan_kernel<<<1, SCAN_T, 0, stream>>>(count, off_work);
    scatter_kernel<<<EB, 256, 0, stream>>>(src, dst, off_work, src_p, ipos);

    // ---- conv1 ----
    gemm_node_kernel<<<GEMM_BLOCKS, 256, 0, stream>>>(x, W1, as1, ad1, A, alpha, beta);
    edge_pass_kernel<<<EB, 256, 0, stream>>>(src, dst, ea, alpha, beta, consts, ipos, ex_p, sdv);
    agg_kernel<0><<<N_NODES, 128, 0, stream>>>(off_work, src_p, ex_p, A, alpha, beta,
                                               b1, sdv, nullptr, nullptr, B);

    // ---- conv2 (+ final linear fused) ----
    gemm_node_kernel<<<GEMM_BLOCKS, 256, 0, stream>>>(B, W2, as2, ad2, A, alpha, beta);
    edge_pass_kernel<<<EB, 256, 0, stream>>>(src, dst, ea, alpha, beta, consts + 32, ipos, ex_p, sdv + 1);
    agg_kernel<1><<<N_NODES, 128, 0, stream>>>(off_work, src_p, ex_p, A, alpha, beta,
                                               b2, sdv + 1, Wl, bl, out);
}

// Round 4
// 551.456 us; speedup vs baseline: 2.4248x; 1.5334x over previous
//
#include <hip/hip_runtime.h>
#include <math.h>

#define N_NODES 50000
#define N_EDGES 800000
#define HIDDEN  128
#define EDIM    32
#define NEG     0.2f

// ---------------------------------------------------------------------------
// ce1 = We1 @ ae1, ce2 = We2 @ ae2 (each [32])
// consts[0:32]=ce1, consts[32:64]=ce2
__global__ void prep_kernel(const float* __restrict__ We1, const float* __restrict__ ae1,
                            const float* __restrict__ We2, const float* __restrict__ ae2,
                            float* __restrict__ consts) {
    int t = threadIdx.x;
    if (t < 32) {
        float acc = 0.f;
        for (int k = 0; k < HIDDEN; k++) acc += We1[t * HIDDEN + k] * ae1[k];
        consts[t] = acc;
    } else if (t < 64) {
        int j = t - 32;
        float acc = 0.f;
        for (int k = 0; k < HIDDEN; k++) acc += We2[j * HIDDEN + k] * ae2[k];
        consts[32 + j] = acc;
    }
}

// ---------------------------------------------------------------------------
// CSR build step 1: in-degree histogram
__global__ void hist_kernel(const int* __restrict__ dst, int* __restrict__ count) {
    int e = blockIdx.x * blockDim.x + threadIdx.x;
    if (e < N_EDGES) atomicAdd(&count[dst[e]], 1);
}

// CSR build step 2: exclusive scan of count -> off_work (single block)
#define SCAN_T 1024
__global__ void scan_kernel(const int* __restrict__ count, int* __restrict__ off_work) {
    __shared__ int part[SCAN_T];
    int t = threadIdx.x;
    const int CH = (N_NODES + SCAN_T - 1) / SCAN_T;   // 49
    int base = t * CH;
    int s = 0;
    for (int i = 0; i < CH; i++) {
        int idx = base + i;
        if (idx < N_NODES) s += count[idx];
    }
    part[t] = s;
    __syncthreads();
    for (int off = 1; off < SCAN_T; off <<= 1) {
        int v = (t >= off) ? part[t - off] : 0;
        __syncthreads();
        part[t] += v;
        __syncthreads();
    }
    int run = (t == 0) ? 0 : part[t - 1];
    for (int i = 0; i < CH; i++) {
        int idx = base + i;
        if (idx < N_NODES) { off_work[idx] = run; run += count[idx]; }
    }
}

// CSR build step 3: scatter edges into dst-sorted order.
// After: off_work[i] == end offset of segment i; off_work[i-1] == start.
__global__ void scatter_kernel(const int* __restrict__ src, const int* __restrict__ dst,
                               int* __restrict__ off_work,
                               int* __restrict__ src_p, int* __restrict__ ipos) {
    int e = blockIdx.x * blockDim.x + threadIdx.x;
    if (e >= N_EDGES) return;
    int pos = atomicAdd(&off_work[dst[e]], 1);
    src_p[pos] = src[e];
    ipos[e] = pos;
}

// ---------------------------------------------------------------------------
// ONE coalesced pass over ea computing BOTH layers' edge scalars:
//   d1 = ea_e . ce1 ; d2 = ea_e . ce2
// scatter-store float2(d1,d2) into dst-sorted slot; accumulate sums of d1,d2
// into 64 padded partial slots (low-contention atomics).
__global__ void dotv_kernel(const float* __restrict__ ea, const float* __restrict__ consts,
                            const int* __restrict__ ipos,
                            float2* __restrict__ dotv_p, float* __restrict__ part) {
    __shared__ float cs[64];
    int t = threadIdx.x;
    if (t < 64) cs[t] = consts[t];
    __syncthreads();
    int e = blockIdx.x * blockDim.x + t;   // N_EDGES % 256 == 0
    const float4* ep = (const float4*)(ea + (size_t)e * EDIM);
    float d1 = 0.f, d2 = 0.f;
#pragma unroll
    for (int i = 0; i < 8; i++) {
        float4 v = ep[i];
        d1 += v.x * cs[4 * i] + v.y * cs[4 * i + 1] + v.z * cs[4 * i + 2] + v.w * cs[4 * i + 3];
        d2 += v.x * cs[32 + 4 * i] + v.y * cs[32 + 4 * i + 1] + v.z * cs[32 + 4 * i + 2] + v.w * cs[32 + 4 * i + 3];
    }
    dotv_p[ipos[e]] = make_float2(d1, d2);
    float s1 = d1, s2 = d2;
    for (int off = 32; off > 0; off >>= 1) {
        s1 += __shfl_down(s1, off, 64);
        s2 += __shfl_down(s2, off, 64);
    }
    if ((t & 63) == 0) {
        int slot = (blockIdx.x & 63) * 16;
        atomicAdd(&part[slot], s1);
        atomicAdd(&part[slot + 1], s2);
    }
}

// reduce the 64 padded partial slots -> sdv[0], sdv[1]  (single wave)
__global__ void reduce_sdv_kernel(const float* __restrict__ part, float* __restrict__ sdv) {
    int t = threadIdx.x;   // 64 threads
    float s1 = part[t * 16], s2 = part[t * 16 + 1];
    for (int off = 32; off > 0; off >>= 1) {
        s1 += __shfl_down(s1, off, 64);
        s2 += __shfl_down(s2, off, 64);
    }
    if (t == 0) { sdv[0] = s1; sdv[1] = s2; }
}

// ---------------------------------------------------------------------------
// h = x @ W with W staged in LDS; 100 rows/block, 4-row chunks, 2 rows/thread.
// fused: alpha[row] = h_row . a_s ; beta[row] = h_row . a_d
#define GEMM_ROWS 100
#define GEMM_BLOCKS (N_NODES / GEMM_ROWS)   // 500
__global__ void __launch_bounds__(256)
gemm_node_kernel(const float* __restrict__ x, const float* __restrict__ W,
                 const float* __restrict__ a_s, const float* __restrict__ a_d,
                 float* __restrict__ h, float* __restrict__ alpha,
                 float* __restrict__ beta) {
    __shared__ float Wl[HIDDEN][HIDDEN];      // 64 KB, [k][col]
    __shared__ float xs[4][HIDDEN];
    __shared__ float pa[4][2], pb[4][2];
    int t = threadIdx.x;
    {
        float4* Wl4 = (float4*)&Wl[0][0];
        const float4* W4 = (const float4*)W;
#pragma unroll
        for (int i = 0; i < 16; i++) Wl4[i * 256 + t] = W4[i * 256 + t];
    }
    int col = t & 127;
    int rq  = t >> 7;          // 0/1 -> which row pair
    int wv  = t >> 6;          // wave id 0..3
    float as_c = a_s[col], ad_c = a_d[col];
    int row_base = blockIdx.x * GEMM_ROWS;
    for (int r0 = row_base; r0 < row_base + GEMM_ROWS; r0 += 4) {
        __syncthreads();
        {
            int j = t >> 7, c = t & 127;
            xs[j][c]     = x[(size_t)(r0 + j) * HIDDEN + c];
            xs[j + 2][c] = x[(size_t)(r0 + j + 2) * HIDDEN + c];
        }
        __syncthreads();
        int ra = r0 + 2 * rq;
        float acc_a = 0.f, acc_b = 0.f;
#pragma unroll 32
        for (int k = 0; k < HIDDEN; k++) {
            float w = Wl[k][col];
            acc_a += xs[2 * rq][k] * w;
            acc_b += xs[2 * rq + 1][k] * w;
        }
        h[(size_t)ra * HIDDEN + col]       = acc_a;
        h[(size_t)(ra + 1) * HIDDEN + col] = acc_b;
        float vaa = acc_a * as_c, vab = acc_b * as_c;
        float vba = acc_a * ad_c, vbb = acc_b * ad_c;
        for (int off = 32; off > 0; off >>= 1) {
            vaa += __shfl_down(vaa, off, 64);
            vab += __shfl_down(vab, off, 64);
            vba += __shfl_down(vba, off, 64);
            vbb += __shfl_down(vbb, off, 64);
        }
        if ((t & 63) == 0) {
            pa[wv][0] = vaa; pa[wv][1] = vab;
            pb[wv][0] = vba; pb[wv][1] = vbb;
        }
        __syncthreads();
        if (t < 4) {
            int rqj = t >> 1, sub = t & 1;
            alpha[r0 + t] = pa[2 * rqj][sub] + pa[2 * rqj + 1][sub];
            beta[r0 + t]  = pb[2 * rqj][sub] + pb[2 * rqj + 1][sub];
        }
    }
}

// ---------------------------------------------------------------------------
// Gather-aggregate; edge weights computed INLINE during staging:
//   w = exp(leaky(alpha[src] + beta[i] + dotv))
// Fused with softmax denominator + self-loop + finalize.
// One block per destination node; 128 threads = channels.
// LAYER: 0 -> use dotv.x, sdv[0]; 1 -> dotv.y, sdv[1]
// FINAL==0: write relu(v + b) to outp[N,128]   (conv1)
// FINAL==1: out[i] = relu(dot(v + b, Wl) + bl) (conv2 + final linear)
template<int LAYER, int FINAL>
__global__ void agg_kernel(const int* __restrict__ off_work,
                           const int* __restrict__ src_p,
                           const float2* __restrict__ dotv_p,
                           const float* __restrict__ h,
                           const float* __restrict__ alpha, const float* __restrict__ beta,
                           const float* __restrict__ b, const float* __restrict__ sdv,
                           const float* __restrict__ Wl, const float* __restrict__ bl,
                           float* __restrict__ outp) {
    __shared__ int   s_src[128];
    __shared__ float s_w[128];
    __shared__ float p[2];
    int i = blockIdx.x, t = threadIdx.x;
    int start = (i == 0) ? 0 : off_work[i - 1];
    int end   = off_work[i];
    float beta_i = beta[i];
    float acc = 0.f, wsum = 0.f;
    for (int cb = start; cb < end; cb += 128) {
        int n = min(128, end - cb);
        __syncthreads();
        if (t < n) {
            int sp = src_p[cb + t];
            float2 dv = dotv_p[cb + t];
            float l = alpha[sp] + beta_i + (LAYER == 0 ? dv.x : dv.y);
            l = l > 0.f ? l : NEG * l;
            s_src[t] = sp;
            s_w[t] = expf(l);
        }
        __syncthreads();
        for (int j = 0; j < n; j++) {
            float w = s_w[j];
            acc  += w * h[(size_t)s_src[j] * HIDDEN + t];
            wsum += w;
        }
    }
    // self-loop edge (edge feature = mean over edges of dotv)
    float selfc = sdv[LAYER] * (1.f / (float)N_EDGES);
    float l = alpha[i] + beta_i + selfc;
    l = l > 0.f ? l : NEG * l;
    float exi = expf(l);
    float denom = wsum + exi + 1e-16f;
    float v = (acc + exi * h[(size_t)i * HIDDEN + t]) / denom + b[t];
    if (FINAL == 0) {
        outp[(size_t)i * HIDDEN + t] = fmaxf(v, 0.f);
    } else {
        float contrib = v * Wl[t];
        for (int off = 32; off > 0; off >>= 1) contrib += __shfl_down(contrib, off, 64);
        if ((t & 63) == 0) p[t >> 6] = contrib;
        __syncthreads();
        if (t == 0) outp[i] = fmaxf(p[0] + p[1] + bl[0], 0.f);
    }
}

// ---------------------------------------------------------------------------
extern "C" void kernel_launch(void* const* d_in, const int* in_sizes, int n_in,
                              void* d_out, int out_size, void* d_ws, size_t ws_size,
                              hipStream_t stream) {
    const float* x   = (const float*)d_in[0];
    const int*   src = (const int*)  d_in[1];
    const int*   dst = (const int*)  d_in[2];
    const float* ea  = (const float*)d_in[3];
    const float* W1  = (const float*)d_in[4];
    const float* We1 = (const float*)d_in[5];
    const float* as1 = (const float*)d_in[6];
    const float* ad1 = (const float*)d_in[7];
    const float* ae1 = (const float*)d_in[8];
    const float* b1  = (const float*)d_in[9];
    const float* W2  = (const float*)d_in[10];
    const float* We2 = (const float*)d_in[11];
    const float* as2 = (const float*)d_in[12];
    const float* ad2 = (const float*)d_in[13];
    const float* ae2 = (const float*)d_in[14];
    const float* b2  = (const float*)d_in[15];
    const float* Wl  = (const float*)d_in[16];
    const float* bl  = (const float*)d_in[17];
    float* out = (float*)d_out;

    float* ws      = (float*)d_ws;
    float* A       = ws;                           // [N*128]  h1, then h2
    float* B       = A + (size_t)N_NODES * HIDDEN; // [N*128]  out1 (conv1 result)
    float* alpha   = B + (size_t)N_NODES * HIDDEN; // [N]
    float* beta    = alpha + N_NODES;              // [N]
    float2* dotv_p = (float2*)(beta + N_NODES);    // [E] (d1,d2) dst-sorted
    float* consts  = (float*)(dotv_p + N_EDGES);   // [64] ce1, ce2
    float* part    = consts + 64;                  // [64*16] padded partials
    float* sdv     = part + 64 * 16;               // [2]
    int* count     = (int*)(sdv + 2);              // [N]
    int* off_work  = count + N_NODES;              // [N]
    int* src_p     = off_work + N_NODES;           // [E] dst-sorted src ids
    int* ipos      = src_p + N_EDGES;              // [E] edge -> sorted slot

    const int EB = (N_EDGES + 255) / 256;

    // ---- prep: edge-logit constants, CSR build, single ea pass ----
    hipMemsetAsync(count, 0, N_NODES * sizeof(int), stream);
    hipMemsetAsync(part, 0, 64 * 16 * sizeof(float), stream);
    prep_kernel<<<1, 64, 0, stream>>>(We1, ae1, We2, ae2, consts);
    hist_kernel<<<EB, 256, 0, stream>>>(dst, count);
    scan_kernel<<<1, SCAN_T, 0, stream>>>(count, off_work);
    scatter_kernel<<<EB, 256, 0, stream>>>(src, dst, off_work, src_p, ipos);
    dotv_kernel<<<EB, 256, 0, stream>>>(ea, consts, ipos, dotv_p, part);
    reduce_sdv_kernel<<<1, 64, 0, stream>>>(part, sdv);

    // ---- conv1 ----
    gemm_node_kernel<<<GEMM_BLOCKS, 256, 0, stream>>>(x, W1, as1, ad1, A, alpha, beta);
    agg_kernel<0, 0><<<N_NODES, 128, 0, stream>>>(off_work, src_p, dotv_p, A, alpha, beta,
                                                  b1, sdv, nullptr, nullptr, B);

    // ---- conv2 (+ final linear fused) ----
    gemm_node_kernel<<<GEMM_BLOCKS, 256, 0, stream>>>(B, W2, as2, ad2, A, alpha, beta);
    agg_kernel<1, 1><<<N_NODES, 128, 0, stream>>>(off_work, src_p, dotv_p, A, alpha, beta,
                                                  b2, sdv, Wl, bl, out);
}

// Round 5
// 479.991 us; speedup vs baseline: 2.7858x; 1.1489x over previous
//
#include <hip/hip_runtime.h>
#include <math.h>

#define N_NODES 50000
#define N_EDGES 800000
#define HIDDEN  128
#define EDIM    32
#define NEG     0.2f

// ---------------------------------------------------------------------------
// ce1 = We1 @ ae1, ce2 = We2 @ ae2 (each [32])
// consts[0:32]=ce1, consts[32:64]=ce2
__global__ void prep_kernel(const float* __restrict__ We1, const float* __restrict__ ae1,
                            const float* __restrict__ We2, const float* __restrict__ ae2,
                            float* __restrict__ consts) {
    int t = threadIdx.x;
    if (t < 32) {
        float acc = 0.f;
        for (int k = 0; k < HIDDEN; k++) acc += We1[t * HIDDEN + k] * ae1[k];
        consts[t] = acc;
    } else if (t < 64) {
        int j = t - 32;
        float acc = 0.f;
        for (int k = 0; k < HIDDEN; k++) acc += We2[j * HIDDEN + k] * ae2[k];
        consts[32 + j] = acc;
    }
}

// ---------------------------------------------------------------------------
// CSR build step 1: in-degree histogram
__global__ void hist_kernel(const int* __restrict__ dst, int* __restrict__ count) {
    int e = blockIdx.x * blockDim.x + threadIdx.x;
    if (e < N_EDGES) atomicAdd(&count[dst[e]], 1);
}

// CSR build step 2: exclusive scan of count -> off_work (single block)
#define SCAN_T 1024
__global__ void scan_kernel(const int* __restrict__ count, int* __restrict__ off_work) {
    __shared__ int part[SCAN_T];
    int t = threadIdx.x;
    const int CH = (N_NODES + SCAN_T - 1) / SCAN_T;   // 49
    int base = t * CH;
    int s = 0;
    for (int i = 0; i < CH; i++) {
        int idx = base + i;
        if (idx < N_NODES) s += count[idx];
    }
    part[t] = s;
    __syncthreads();
    for (int off = 1; off < SCAN_T; off <<= 1) {
        int v = (t >= off) ? part[t - off] : 0;
        __syncthreads();
        part[t] += v;
        __syncthreads();
    }
    int run = (t == 0) ? 0 : part[t - 1];
    for (int i = 0; i < CH; i++) {
        int idx = base + i;
        if (idx < N_NODES) { off_work[idx] = run; run += count[idx]; }
    }
}

// CSR build step 3: scatter edges into dst-sorted order.
// After: off_work[i] == end offset of segment i; off_work[i-1] == start.
__global__ void scatter_kernel(const int* __restrict__ src, const int* __restrict__ dst,
                               int* __restrict__ off_work,
                               int* __restrict__ src_p, int* __restrict__ ipos) {
    int e = blockIdx.x * blockDim.x + threadIdx.x;
    if (e >= N_EDGES) return;
    int pos = atomicAdd(&off_work[dst[e]], 1);
    src_p[pos] = src[e];
    ipos[e] = pos;
}

// ---------------------------------------------------------------------------
// ONE coalesced pass over ea computing BOTH layers' edge scalars:
//   d1 = ea_e . ce1 ; d2 = ea_e . ce2
// scatter-store float2(d1,d2) into dst-sorted slot; accumulate sums of d1,d2
// into 64 padded partial slots (low-contention atomics).
__global__ void dotv_kernel(const float* __restrict__ ea, const float* __restrict__ consts,
                            const int* __restrict__ ipos,
                            float2* __restrict__ dotv_p, float* __restrict__ part) {
    __shared__ float cs[64];
    int t = threadIdx.x;
    if (t < 64) cs[t] = consts[t];
    __syncthreads();
    int e = blockIdx.x * blockDim.x + t;   // N_EDGES % 256 == 0
    const float4* ep = (const float4*)(ea + (size_t)e * EDIM);
    float d1 = 0.f, d2 = 0.f;
#pragma unroll
    for (int i = 0; i < 8; i++) {
        float4 v = ep[i];
        d1 += v.x * cs[4 * i] + v.y * cs[4 * i + 1] + v.z * cs[4 * i + 2] + v.w * cs[4 * i + 3];
        d2 += v.x * cs[32 + 4 * i] + v.y * cs[32 + 4 * i + 1] + v.z * cs[32 + 4 * i + 2] + v.w * cs[32 + 4 * i + 3];
    }
    dotv_p[ipos[e]] = make_float2(d1, d2);
    float s1 = d1, s2 = d2;
    for (int off = 32; off > 0; off >>= 1) {
        s1 += __shfl_down(s1, off, 64);
        s2 += __shfl_down(s2, off, 64);
    }
    if ((t & 63) == 0) {
        int slot = (blockIdx.x & 63) * 16;
        atomicAdd(&part[slot], s1);
        atomicAdd(&part[slot + 1], s2);
    }
}

// reduce the 64 padded partial slots -> sdv[0], sdv[1]  (single wave)
__global__ void reduce_sdv_kernel(const float* __restrict__ part, float* __restrict__ sdv) {
    int t = threadIdx.x;   // 64 threads
    float s1 = part[t * 16], s2 = part[t * 16 + 1];
    for (int off = 32; off > 0; off >>= 1) {
        s1 += __shfl_down(s1, off, 64);
        s2 += __shfl_down(s2, off, 64);
    }
    if (t == 0) { sdv[0] = s1; sdv[1] = s2; }
}

// ---------------------------------------------------------------------------
// h = x @ W, register-resident W column per thread, scalar (SGPR) x operands.
// 128 threads = 128 output cols; W[k][col] in 128 VGPRs (static unroll).
// Inner loop is pure v_fmac (no LDS). 4 independent row-accumulators for ILP.
// fused: alpha[row] = h_row . a_s ; beta[row] = h_row . a_d
#define GR_PER_BLOCK 40
#define G_CHUNK 4
#define GEMM_BLOCKS (N_NODES / GR_PER_BLOCK)   // 1250
__global__ void __launch_bounds__(128)
gemm_node_kernel(const float* __restrict__ x, const float* __restrict__ W,
                 const float* __restrict__ a_s, const float* __restrict__ a_d,
                 float* __restrict__ h, float* __restrict__ alpha,
                 float* __restrict__ beta) {
    __shared__ float pa[2][G_CHUNK], pb[2][G_CHUNK];
    int col = threadIdx.x;             // 0..127
    float wreg[HIDDEN];
#pragma unroll
    for (int k = 0; k < HIDDEN; k++) wreg[k] = W[k * HIDDEN + col];  // coalesced
    float as_c = a_s[col], ad_c = a_d[col];
    int row0 = blockIdx.x * GR_PER_BLOCK;
    for (int r0 = row0; r0 < row0 + GR_PER_BLOCK; r0 += G_CHUNK) {
        float acc[G_CHUNK];
#pragma unroll
        for (int r = 0; r < G_CHUNK; r++) acc[r] = 0.f;
        const float* xr = x + (size_t)r0 * HIDDEN;
#pragma unroll
        for (int k = 0; k < HIDDEN; k++) {
#pragma unroll
            for (int r = 0; r < G_CHUNK; r++)
                acc[r] += xr[r * HIDDEN + k] * wreg[k];   // scalar x, VGPR w
        }
#pragma unroll
        for (int r = 0; r < G_CHUNK; r++)
            h[(size_t)(r0 + r) * HIDDEN + col] = acc[r];
        // alpha/beta reductions for the 4 rows
#pragma unroll
        for (int r = 0; r < G_CHUNK; r++) {
            float va = acc[r] * as_c;
            float vb = acc[r] * ad_c;
            for (int off = 32; off > 0; off >>= 1) {
                va += __shfl_down(va, off, 64);
                vb += __shfl_down(vb, off, 64);
            }
            if ((col & 63) == 0) { pa[col >> 6][r] = va; pb[col >> 6][r] = vb; }
        }
        __syncthreads();
        if (col < G_CHUNK) {
            alpha[r0 + col] = pa[0][col] + pa[1][col];
            beta[r0 + col]  = pb[0][col] + pb[1][col];
        }
        __syncthreads();
    }
}

// ---------------------------------------------------------------------------
// Gather-aggregate: ONE WAVE PER NODE (4 nodes / 256-block, no barriers).
// Lane l owns channels 2l, 2l+1 (float2). Edge weights computed inline:
//   w = exp(leaky(alpha[src] + beta[i] + dotv)); broadcast via __shfl.
// Fused softmax denominator + self-loop + finalize.
// FINAL==0: write relu(v + b) to outp[N,128]   (conv1)
// FINAL==1: out[i] = relu(dot(v + b, Wl) + bl) (conv2 + final linear)
template<int LAYER, int FINAL>
__global__ void __launch_bounds__(256)
agg_kernel(const int* __restrict__ off_work,
           const int* __restrict__ src_p,
           const float2* __restrict__ dotv_p,
           const float* __restrict__ h,
           const float* __restrict__ alpha, const float* __restrict__ beta,
           const float* __restrict__ b, const float* __restrict__ sdv,
           const float* __restrict__ Wl, const float* __restrict__ bl,
           float* __restrict__ outp) {
    int t = threadIdx.x;
    int l = t & 63;
    int i = blockIdx.x * 4 + (t >> 6);       // node id (grid covers N exactly)
    int start = (i == 0) ? 0 : off_work[i - 1];
    int end   = off_work[i];
    float beta_i = beta[i];
    float2 acc = make_float2(0.f, 0.f);
    float wsum = 0.f;
    for (int cb = start; cb < end; cb += 64) {
        int n = min(64, end - cb);
        int sp = 0; float wt = 0.f;
        if (l < n) {
            sp = src_p[cb + l];
            float2 dv = dotv_p[cb + l];
            float lg = alpha[sp] + beta_i + (LAYER == 0 ? dv.x : dv.y);
            lg = lg > 0.f ? lg : NEG * lg;
            wt = expf(lg);
        }
        for (int j = 0; j < n; j++) {
            float w = __shfl(wt, j, 64);
            int   sj = __shfl(sp, j, 64);
            float2 hv = ((const float2*)(h + (size_t)sj * HIDDEN))[l];
            acc.x += w * hv.x;
            acc.y += w * hv.y;
            wsum  += w;
        }
    }
    // self-loop edge (edge feature = mean over edges of dotv)
    float selfc = sdv[LAYER] * (1.f / (float)N_EDGES);
    float lg = alpha[i] + beta_i + selfc;
    lg = lg > 0.f ? lg : NEG * lg;
    float exi = expf(lg);
    float denom = wsum + exi + 1e-16f;
    float2 hv = ((const float2*)(h + (size_t)i * HIDDEN))[l];
    float2 bb = ((const float2*)b)[l];
    float2 v;
    v.x = (acc.x + exi * hv.x) / denom + bb.x;
    v.y = (acc.y + exi * hv.y) / denom + bb.y;
    if (FINAL == 0) {
        ((float2*)(outp + (size_t)i * HIDDEN))[l] =
            make_float2(fmaxf(v.x, 0.f), fmaxf(v.y, 0.f));
    } else {
        float2 wl = ((const float2*)Wl)[l];
        float contrib = v.x * wl.x + v.y * wl.y;
        for (int off = 32; off > 0; off >>= 1) contrib += __shfl_down(contrib, off, 64);
        if (l == 0) outp[i] = fmaxf(contrib + bl[0], 0.f);
    }
}

// ---------------------------------------------------------------------------
extern "C" void kernel_launch(void* const* d_in, const int* in_sizes, int n_in,
                              void* d_out, int out_size, void* d_ws, size_t ws_size,
                              hipStream_t stream) {
    const float* x   = (const float*)d_in[0];
    const int*   src = (const int*)  d_in[1];
    const int*   dst = (const int*)  d_in[2];
    const float* ea  = (const float*)d_in[3];
    const float* W1  = (const float*)d_in[4];
    const float* We1 = (const float*)d_in[5];
    const float* as1 = (const float*)d_in[6];
    const float* ad1 = (const float*)d_in[7];
    const float* ae1 = (const float*)d_in[8];
    const float* b1  = (const float*)d_in[9];
    const float* W2  = (const float*)d_in[10];
    const float* We2 = (const float*)d_in[11];
    const float* as2 = (const float*)d_in[12];
    const float* ad2 = (const float*)d_in[13];
    const float* ae2 = (const float*)d_in[14];
    const float* b2  = (const float*)d_in[15];
    const float* Wl  = (const float*)d_in[16];
    const float* bl  = (const float*)d_in[17];
    float* out = (float*)d_out;

    float* ws      = (float*)d_ws;
    float* A       = ws;                           // [N*128]  h1, then h2
    float* B       = A + (size_t)N_NODES * HIDDEN; // [N*128]  out1 (conv1 result)
    float* alpha   = B + (size_t)N_NODES * HIDDEN; // [N]
    float* beta    = alpha + N_NODES;              // [N]
    float2* dotv_p = (float2*)(beta + N_NODES);    // [E] (d1,d2) dst-sorted
    float* consts  = (float*)(dotv_p + N_EDGES);   // [64] ce1, ce2
    float* part    = consts + 64;                  // [64*16] padded partials
    float* sdv     = part + 64 * 16;               // [2]
    int* count     = (int*)(sdv + 2);              // [N]
    int* off_work  = count + N_NODES;              // [N]
    int* src_p     = off_work + N_NODES;           // [E] dst-sorted src ids
    int* ipos      = src_p + N_EDGES;              // [E] edge -> sorted slot

    const int EB = (N_EDGES + 255) / 256;

    // ---- prep: edge-logit constants, CSR build, single ea pass ----
    hipMemsetAsync(count, 0, N_NODES * sizeof(int), stream);
    hipMemsetAsync(part, 0, 64 * 16 * sizeof(float), stream);
    prep_kernel<<<1, 64, 0, stream>>>(We1, ae1, We2, ae2, consts);
    hist_kernel<<<EB, 256, 0, stream>>>(dst, count);
    scan_kernel<<<1, SCAN_T, 0, stream>>>(count, off_work);
    scatter_kernel<<<EB, 256, 0, stream>>>(src, dst, off_work, src_p, ipos);
    dotv_kernel<<<EB, 256, 0, stream>>>(ea, consts, ipos, dotv_p, part);
    reduce_sdv_kernel<<<1, 64, 0, stream>>>(part, sdv);

    // ---- conv1 ----
    gemm_node_kernel<<<GEMM_BLOCKS, 128, 0, stream>>>(x, W1, as1, ad1, A, alpha, beta);
    agg_kernel<0, 0><<<N_NODES / 4, 256, 0, stream>>>(off_work, src_p, dotv_p, A, alpha, beta,
                                                      b1, sdv, nullptr, nullptr, B);

    // ---- conv2 (+ final linear fused) ----
    gemm_node_kernel<<<GEMM_BLOCKS, 128, 0, stream>>>(B, W2, as2, ad2, A, alpha, beta);
    agg_kernel<1, 1><<<N_NODES / 4, 256, 0, stream>>>(off_work, src_p, dotv_p, A, alpha, beta,
                                                      b2, sdv, Wl, bl, out);
}

// Round 6
// 393.585 us; speedup vs baseline: 3.3974x; 1.2195x over previous
//
#include <hip/hip_runtime.h>
#include <math.h>

#define N_NODES 50000
#define N_EDGES 800000
#define HIDDEN  128
#define EDIM    32
#define NEG     0.2f

// ---------------------------------------------------------------------------
// ce1 = We1 @ ae1, ce2 = We2 @ ae2 (each [32])
// consts[0:32]=ce1, consts[32:64]=ce2
__global__ void prep_kernel(const float* __restrict__ We1, const float* __restrict__ ae1,
                            const float* __restrict__ We2, const float* __restrict__ ae2,
                            float* __restrict__ consts) {
    int t = threadIdx.x;
    if (t < 32) {
        float acc = 0.f;
        for (int k = 0; k < HIDDEN; k++) acc += We1[t * HIDDEN + k] * ae1[k];
        consts[t] = acc;
    } else if (t < 64) {
        int j = t - 32;
        float acc = 0.f;
        for (int k = 0; k < HIDDEN; k++) acc += We2[j * HIDDEN + k] * ae2[k];
        consts[32 + j] = acc;
    }
}

// ---------------------------------------------------------------------------
// CSR build step 1: in-degree histogram
__global__ void hist_kernel(const int* __restrict__ dst, int* __restrict__ count) {
    int e = blockIdx.x * blockDim.x + threadIdx.x;
    if (e < N_EDGES) atomicAdd(&count[dst[e]], 1);
}

// ---------------------------------------------------------------------------
// CSR build step 2: 3-phase parallel exclusive scan of count -> off_work
#define SCAN_BLOCKS ((N_NODES + 255) / 256)   // 196
// phase 1: per-block exclusive scan over a 256-chunk + block total
__global__ void scan1_kernel(const int* __restrict__ count,
                             int* __restrict__ off_work, int* __restrict__ blocksum) {
    __shared__ int sh[256];
    int t = threadIdx.x;
    int idx = blockIdx.x * 256 + t;
    int v = (idx < N_NODES) ? count[idx] : 0;
    sh[t] = v;
    __syncthreads();
    for (int off = 1; off < 256; off <<= 1) {
        int u = (t >= off) ? sh[t - off] : 0;
        __syncthreads();
        sh[t] += u;
        __syncthreads();
    }
    if (idx < N_NODES) off_work[idx] = sh[t] - v;          // exclusive in-block
    if (t == 255) blocksum[blockIdx.x] = sh[255];          // block total
}
// phase 2: exclusive scan of the 196 block totals (one block)
__global__ void scan2_kernel(int* __restrict__ blocksum, int* __restrict__ blockoff) {
    __shared__ int sh[256];
    int t = threadIdx.x;
    int v = (t < SCAN_BLOCKS) ? blocksum[t] : 0;
    sh[t] = v;
    __syncthreads();
    for (int off = 1; off < 256; off <<= 1) {
        int u = (t >= off) ? sh[t - off] : 0;
        __syncthreads();
        sh[t] += u;
        __syncthreads();
    }
    if (t < SCAN_BLOCKS) blockoff[t] = sh[t] - v;
}
// phase 3: add block offsets
__global__ void scan3_kernel(int* __restrict__ off_work, const int* __restrict__ blockoff) {
    int idx = blockIdx.x * 256 + threadIdx.x;
    if (idx < N_NODES) off_work[idx] += blockoff[blockIdx.x];
}

// CSR build step 4: scatter edges into dst-sorted order.
// After: off_work[i] == end offset of segment i; off_work[i-1] == start.
__global__ void scatter_kernel(const int* __restrict__ src, const int* __restrict__ dst,
                               int* __restrict__ off_work,
                               int* __restrict__ src_p, int* __restrict__ ipos) {
    int e = blockIdx.x * blockDim.x + threadIdx.x;
    if (e >= N_EDGES) return;
    int pos = atomicAdd(&off_work[dst[e]], 1);
    src_p[pos] = src[e];
    ipos[e] = pos;
}

// ---------------------------------------------------------------------------
// ONE coalesced pass over ea computing BOTH layers' edge scalars:
//   d1 = ea_e . ce1 ; d2 = ea_e . ce2
// scatter-store float2(d1,d2) into dst-sorted slot; accumulate sums of d1,d2
// into 64 padded partial slots (low-contention atomics).
__global__ void dotv_kernel(const float* __restrict__ ea, const float* __restrict__ consts,
                            const int* __restrict__ ipos,
                            float2* __restrict__ dotv_p, float* __restrict__ part) {
    __shared__ float cs[64];
    int t = threadIdx.x;
    if (t < 64) cs[t] = consts[t];
    __syncthreads();
    int e = blockIdx.x * blockDim.x + t;   // N_EDGES % 256 == 0
    const float4* ep = (const float4*)(ea + (size_t)e * EDIM);
    float d1 = 0.f, d2 = 0.f;
#pragma unroll
    for (int i = 0; i < 8; i++) {
        float4 v = ep[i];
        d1 += v.x * cs[4 * i] + v.y * cs[4 * i + 1] + v.z * cs[4 * i + 2] + v.w * cs[4 * i + 3];
        d2 += v.x * cs[32 + 4 * i] + v.y * cs[32 + 4 * i + 1] + v.z * cs[32 + 4 * i + 2] + v.w * cs[32 + 4 * i + 3];
    }
    dotv_p[ipos[e]] = make_float2(d1, d2);
    float s1 = d1, s2 = d2;
    for (int off = 32; off > 0; off >>= 1) {
        s1 += __shfl_down(s1, off, 64);
        s2 += __shfl_down(s2, off, 64);
    }
    if ((t & 63) == 0) {
        int slot = (blockIdx.x & 63) * 16;
        atomicAdd(&part[slot], s1);
        atomicAdd(&part[slot + 1], s2);
    }
}

// reduce the 64 padded partial slots -> sdv[0], sdv[1]  (single wave)
__global__ void reduce_sdv_kernel(const float* __restrict__ part, float* __restrict__ sdv) {
    int t = threadIdx.x;   // 64 threads
    float s1 = part[t * 16], s2 = part[t * 16 + 1];
    for (int off = 32; off > 0; off >>= 1) {
        s1 += __shfl_down(s1, off, 64);
        s2 += __shfl_down(s2, off, 64);
    }
    if (t == 0) { sdv[0] = s1; sdv[1] = s2; }
}

// ---------------------------------------------------------------------------
// h = x @ W, register-resident W column per thread, scalar (SGPR) x operands.
// 128 threads = 128 output cols; W[k][col] in 128 VGPRs (static unroll).
// Inner loop is pure v_fmac (no LDS). 4 independent row-accumulators for ILP.
// fused: alpha[row] = h_row . a_s ; beta[row] = h_row . a_d
#define GR_PER_BLOCK 40
#define G_CHUNK 4
#define GEMM_BLOCKS (N_NODES / GR_PER_BLOCK)   // 1250
__global__ void __launch_bounds__(128)
gemm_node_kernel(const float* __restrict__ x, const float* __restrict__ W,
                 const float* __restrict__ a_s, const float* __restrict__ a_d,
                 float* __restrict__ h, float* __restrict__ alpha,
                 float* __restrict__ beta) {
    __shared__ float pa[2][G_CHUNK], pb[2][G_CHUNK];
    int col = threadIdx.x;             // 0..127
    float wreg[HIDDEN];
#pragma unroll
    for (int k = 0; k < HIDDEN; k++) wreg[k] = W[k * HIDDEN + col];  // coalesced
    float as_c = a_s[col], ad_c = a_d[col];
    int row0 = blockIdx.x * GR_PER_BLOCK;
    for (int r0 = row0; r0 < row0 + GR_PER_BLOCK; r0 += G_CHUNK) {
        float acc[G_CHUNK];
#pragma unroll
        for (int r = 0; r < G_CHUNK; r++) acc[r] = 0.f;
        const float* xr = x + (size_t)r0 * HIDDEN;
#pragma unroll
        for (int k = 0; k < HIDDEN; k++) {
#pragma unroll
            for (int r = 0; r < G_CHUNK; r++)
                acc[r] += xr[r * HIDDEN + k] * wreg[k];   // scalar x, VGPR w
        }
#pragma unroll
        for (int r = 0; r < G_CHUNK; r++)
            h[(size_t)(r0 + r) * HIDDEN + col] = acc[r];
        // alpha/beta reductions for the 4 rows
#pragma unroll
        for (int r = 0; r < G_CHUNK; r++) {
            float va = acc[r] * as_c;
            float vb = acc[r] * ad_c;
            for (int off = 32; off > 0; off >>= 1) {
                va += __shfl_down(va, off, 64);
                vb += __shfl_down(vb, off, 64);
            }
            if ((col & 63) == 0) { pa[col >> 6][r] = va; pb[col >> 6][r] = vb; }
        }
        __syncthreads();
        if (col < G_CHUNK) {
            alpha[r0 + col] = pa[0][col] + pa[1][col];
            beta[r0 + col]  = pb[0][col] + pb[1][col];
        }
        __syncthreads();
    }
}

// ---------------------------------------------------------------------------
// Gather-aggregate: ONE WAVE PER NODE (4 nodes / 256-block, no barriers).
// Lane l owns channels 2l, 2l+1 (float2). Edge weights computed inline:
//   w = exp(leaky(alpha[src] + beta[i] + dotv)); broadcast via __shfl.
// Fused softmax denominator + self-loop + finalize.
// FINAL==0: write relu(v + b) to outp[N,128]   (conv1)
// FINAL==1: out[i] = relu(dot(v + b, Wl) + bl) (conv2 + final linear)
template<int LAYER, int FINAL>
__global__ void __launch_bounds__(256)
agg_kernel(const int* __restrict__ off_work,
           const int* __restrict__ src_p,
           const float2* __restrict__ dotv_p,
           const float* __restrict__ h,
           const float* __restrict__ alpha, const float* __restrict__ beta,
           const float* __restrict__ b, const float* __restrict__ sdv,
           const float* __restrict__ Wl, const float* __restrict__ bl,
           float* __restrict__ outp) {
    int t = threadIdx.x;
    int l = t & 63;
    int i = blockIdx.x * 4 + (t >> 6);       // node id (grid covers N exactly)
    int start = (i == 0) ? 0 : off_work[i - 1];
    int end   = off_work[i];
    float beta_i = beta[i];
    float2 acc = make_float2(0.f, 0.f);
    float wsum = 0.f;
    for (int cb = start; cb < end; cb += 64) {
        int n = min(64, end - cb);
        int sp = 0; float wt = 0.f;
        if (l < n) {
            sp = src_p[cb + l];
            float2 dv = dotv_p[cb + l];
            float lg = alpha[sp] + beta_i + (LAYER == 0 ? dv.x : dv.y);
            lg = lg > 0.f ? lg : NEG * lg;
            wt = expf(lg);
        }
        for (int j = 0; j < n; j++) {
            float w = __shfl(wt, j, 64);
            int   sj = __shfl(sp, j, 64);
            float2 hv = ((const float2*)(h + (size_t)sj * HIDDEN))[l];
            acc.x += w * hv.x;
            acc.y += w * hv.y;
            wsum  += w;
        }
    }
    // self-loop edge (edge feature = mean over edges of dotv)
    float selfc = sdv[LAYER] * (1.f / (float)N_EDGES);
    float lg = alpha[i] + beta_i + selfc;
    lg = lg > 0.f ? lg : NEG * lg;
    float exi = expf(lg);
    float denom = wsum + exi + 1e-16f;
    float2 hv = ((const float2*)(h + (size_t)i * HIDDEN))[l];
    float2 bb = ((const float2*)b)[l];
    float2 v;
    v.x = (acc.x + exi * hv.x) / denom + bb.x;
    v.y = (acc.y + exi * hv.y) / denom + bb.y;
    if (FINAL == 0) {
        ((float2*)(outp + (size_t)i * HIDDEN))[l] =
            make_float2(fmaxf(v.x, 0.f), fmaxf(v.y, 0.f));
    } else {
        float2 wl = ((const float2*)Wl)[l];
        float contrib = v.x * wl.x + v.y * wl.y;
        for (int off = 32; off > 0; off >>= 1) contrib += __shfl_down(contrib, off, 64);
        if (l == 0) outp[i] = fmaxf(contrib + bl[0], 0.f);
    }
}

// ---------------------------------------------------------------------------
extern "C" void kernel_launch(void* const* d_in, const int* in_sizes, int n_in,
                              void* d_out, int out_size, void* d_ws, size_t ws_size,
                              hipStream_t stream) {
    const float* x   = (const float*)d_in[0];
    const int*   src = (const int*)  d_in[1];
    const int*   dst = (const int*)  d_in[2];
    const float* ea  = (const float*)d_in[3];
    const float* W1  = (const float*)d_in[4];
    const float* We1 = (const float*)d_in[5];
    const float* as1 = (const float*)d_in[6];
    const float* ad1 = (const float*)d_in[7];
    const float* ae1 = (const float*)d_in[8];
    const float* b1  = (const float*)d_in[9];
    const float* W2  = (const float*)d_in[10];
    const float* We2 = (const float*)d_in[11];
    const float* as2 = (const float*)d_in[12];
    const float* ad2 = (const float*)d_in[13];
    const float* ae2 = (const float*)d_in[14];
    const float* b2  = (const float*)d_in[15];
    const float* Wl  = (const float*)d_in[16];
    const float* bl  = (const float*)d_in[17];
    float* out = (float*)d_out;

    float* ws      = (float*)d_ws;
    float* A       = ws;                           // [N*128]  h1, then h2
    float* B       = A + (size_t)N_NODES * HIDDEN; // [N*128]  out1 (conv1 result)
    float* alpha   = B + (size_t)N_NODES * HIDDEN; // [N]
    float* beta    = alpha + N_NODES;              // [N]
    float2* dotv_p = (float2*)(beta + N_NODES);    // [E] (d1,d2) dst-sorted
    float* consts  = (float*)(dotv_p + N_EDGES);   // [64] ce1, ce2
    float* part    = consts + 64;                  // [64*16] padded partials
    float* sdv     = part + 64 * 16;               // [2]
    int* count     = (int*)(sdv + 2);              // [N]
    int* off_work  = count + N_NODES;              // [N]
    int* blocksum  = off_work + N_NODES;           // [SCAN_BLOCKS]
    int* blockoff  = blocksum + SCAN_BLOCKS;       // [SCAN_BLOCKS]
    int* src_p     = blockoff + SCAN_BLOCKS;       // [E] dst-sorted src ids
    int* ipos      = src_p + N_EDGES;              // [E] edge -> sorted slot

    const int EB = (N_EDGES + 255) / 256;

    // ---- prep: edge-logit constants, CSR build, single ea pass ----
    hipMemsetAsync(count, 0, N_NODES * sizeof(int), stream);
    hipMemsetAsync(part, 0, 64 * 16 * sizeof(float), stream);
    prep_kernel<<<1, 64, 0, stream>>>(We1, ae1, We2, ae2, consts);
    hist_kernel<<<EB, 256, 0, stream>>>(dst, count);
    scan1_kernel<<<SCAN_BLOCKS, 256, 0, stream>>>(count, off_work, blocksum);
    scan2_kernel<<<1, 256, 0, stream>>>(blocksum, blockoff);
    scan3_kernel<<<SCAN_BLOCKS, 256, 0, stream>>>(off_work, blockoff);
    scatter_kernel<<<EB, 256, 0, stream>>>(src, dst, off_work, src_p, ipos);
    dotv_kernel<<<EB, 256, 0, stream>>>(ea, consts, ipos, dotv_p, part);
    reduce_sdv_kernel<<<1, 64, 0, stream>>>(part, sdv);

    // ---- conv1 ----
    gemm_node_kernel<<<GEMM_BLOCKS, 128, 0, stream>>>(x, W1, as1, ad1, A, alpha, beta);
    agg_kernel<0, 0><<<N_NODES / 4, 256, 0, stream>>>(off_work, src_p, dotv_p, A, alpha, beta,
                                                      b1, sdv, nullptr, nullptr, B);

    // ---- conv2 (+ final linear fused) ----
    gemm_node_kernel<<<GEMM_BLOCKS, 128, 0, stream>>>(B, W2, as2, ad2, A, alpha, beta);
    agg_kernel<1, 1><<<N_NODES / 4, 256, 0, stream>>>(off_work, src_p, dotv_p, A, alpha, beta,
                                                      b2, sdv, Wl, bl, out);
}